// Round 6
// baseline (330.868 us; speedup 1.0000x reference)
//
#include <hip/hip_runtime.h>
#include <hip/hip_bf16.h>

typedef unsigned int uint;

// B=2, N=512, D=256, H=8, HD=32, DFF=1024
constexpr float EPS_ = 1e-5f;

#define DEV __device__ __forceinline__

DEV float gelu_(float x){ return 0.5f*x*(1.f + erff(x*0.70710678118654752f)); }

// block = 256 threads (4 waves)
DEV float blockSum256(float v, float* red){
    #pragma unroll
    for (int o = 32; o >= 1; o >>= 1) v += __shfl_xor(v, o);
    int t = threadIdx.x;
    __syncthreads();                    // protect red from previous use
    if ((t & 63) == 0) red[t >> 6] = v;
    __syncthreads();
    return red[0]+red[1]+red[2]+red[3];
}

// ---------------- setup: GW[d][h]=g_d*We[d,h], A[h]=sum GW, C[h]=sum b_d*We+be ----------------
__global__ __launch_bounds__(256) void k_setup(
    const float* __restrict__ g, const float* __restrict__ b,
    const float* __restrict__ We, const float* __restrict__ be,
    float* __restrict__ GW, float* __restrict__ A, float* __restrict__ C)
{
    const int d = threadIdx.x;
    __shared__ float redA[256*8];
    __shared__ float redC[256*8];
    float gd = g[d], bd = b[d];
    #pragma unroll
    for (int h = 0; h < 8; ++h) {
        float w = We[d*8+h];
        float gw = gd*w;
        GW[d*8+h] = gw;
        redA[d*8+h] = gw;
        redC[d*8+h] = bd*w;
    }
    __syncthreads();
    for (int s = 128; s >= 1; s >>= 1) {
        if (d < s) {
            #pragma unroll
            for (int h = 0; h < 8; ++h) {
                redA[d*8+h] += redA[(d+s)*8+h];
                redC[d*8+h] += redC[(d+s)*8+h];
            }
        }
        __syncthreads();
    }
    if (d < 8) {
        A[d] = redA[d];
        C[d] = redC[d] + be[d];
    }
}

// ---------------- node LN + QKV projection, output (B,N,D) ----------------
__global__ __launch_bounds__(256) void k_qkv(
    const float* __restrict__ x,
    const float* __restrict__ g, const float* __restrict__ bta,
    const float* __restrict__ Wq, const float* __restrict__ bq,
    const float* __restrict__ Wk, const float* __restrict__ bk,
    const float* __restrict__ Wv, const float* __restrict__ bv,
    float* __restrict__ q, float* __restrict__ k, float* __restrict__ v)
{
    const int row = blockIdx.x;           // b*512 + n
    const int t = threadIdx.x;
    __shared__ float sx[256];
    __shared__ float red[4];
    float xv = x[row*256 + t];
    float s1 = blockSum256(xv, red);
    float s2 = blockSum256(xv*xv, red);
    float m = s1 * (1.f/256.f);
    float rinv = rsqrtf(s2*(1.f/256.f) - m*m + EPS_);
    sx[t] = (xv - m) * rinv * g[t] + bta[t];
    __syncthreads();
    float aq = bq[t], ak = bk[t], av = bv[t];
    for (int d = 0; d < 256; ++d) {
        float s = sx[d];
        aq = fmaf(s, Wq[d*256 + t], aq);
        ak = fmaf(s, Wk[d*256 + t], ak);
        av = fmaf(s, Wv[d*256 + t], av);
    }
    q[row*256 + t] = aq;
    k[row*256 + t] = ak;
    v[row*256 + t] = av;
}

// ---------------- fused: edge LN->bias->mask + attention for one (b,i) ----------------
// 256 threads. Edge rows (b,i,0..511) staged in 2 halves; thread owns one row per half.
// LDS slds padded to 33 floats/row-chunk (stride 33 mod 32 = 1 -> <=2-way aliasing, free).
__global__ __launch_bounds__(256) void k_eattn(
    const float4* __restrict__ ep,        // edge as float4: 64 per 256-elem row
    const int*   __restrict__ msk,        // (B,N,N)
    const float* __restrict__ GW, const float* __restrict__ Avec, const float* __restrict__ Cvec,
    const float* __restrict__ qg, const float* __restrict__ kg, const float* __restrict__ vg,
    float* __restrict__ ao)               // (B,N,D) f32
{
    __shared__ float slds[256*33];        // 33792 B staging
    __shared__ float sgw[2048];           // 8 KB GW table
    __shared__ float sac[16];
    __shared__ float sb[8*512];           // [h][j] bias + mask, 16 KB
    __shared__ float sp[8*512];           // [h][j] probs, 16 KB
    __shared__ float sqv[256];            // q row, pre-scaled
    __shared__ float sden[8];
    const int t = threadIdx.x;
    const int bi = blockIdx.x;            // b*512 + i
    const int b = bi >> 9;
    #pragma unroll
    for (int kk = 0; kk < 8; ++kk) sgw[kk*256 + t] = GW[kk*256 + t];
    if (t < 8) { sac[t] = Avec[t]; sac[8 + t] = Cvec[t]; }
    sqv[t] = qg[(size_t)bi*256 + t] * 0.17677669529663687f;   // 1/sqrt(32)
    __syncthreads();

    // ---- edge bias for all 512 keys, two halves of 256 rows ----
    for (int half = 0; half < 2; ++half) {
        const long long rowBase = ((long long)bi << 9) + (half << 8);  // (b,i,j0)
        float sum = 0.f, ssq = 0.f;
        float S[8] = {0.f,0.f,0.f,0.f,0.f,0.f,0.f,0.f};
        for (int c = 0; c < 8; ++c) {     // 8 chunks of 32 floats per row
            #pragma unroll
            for (int kk = 0; kk < 8; ++kk) {
                int l2 = (kk << 8) + t;
                int r = l2 >> 3, u = l2 & 7;
                float4 val = ep[(rowBase + r)*64 + (c << 3) + u];
                float* dst = &slds[r*33 + (u << 2)];
                dst[0] = val.x; dst[1] = val.y; dst[2] = val.z; dst[3] = val.w;
            }
            __syncthreads();
            const float* srow = &slds[t*33];
            const int dbase = c << 5;
            #pragma unroll 4
            for (int j = 0; j < 32; ++j) {
                float e = srow[j];
                const float* g0 = &sgw[(dbase + j) << 3];  // uniform addr -> broadcast
                sum += e;
                ssq = fmaf(e, e, ssq);
                #pragma unroll
                for (int h = 0; h < 8; ++h) S[h] = fmaf(e, g0[h], S[h]);
            }
            __syncthreads();
        }
        const float m = sum * (1.f/256.f);
        const float rinv = rsqrtf(ssq*(1.f/256.f) - m*m + EPS_);
        const float mb = (msk[rowBase + t] == 0) ? -1e30f : 0.f;
        const int jrow = (half << 8) + t;
        #pragma unroll
        for (int h = 0; h < 8; ++h)
            sb[h*512 + jrow] = rinv * (S[h] - m * sac[h]) + sac[8 + h] + mb;
    }
    __syncthreads();                      // sb complete

    // ---- scores + softmax: head h = t>>5, lane l = t&31 owns keys j = l + 32m ----
    const int h = t >> 5, l = t & 31;
    const float* kb = kg + ((size_t)b << 9)*256 + h*32;
    const float4* qr = (const float4*)(sqv + h*32);
    float sc[16];
    float pmax = -3.0e38f;
    #pragma unroll
    for (int mi = 0; mi < 16; ++mi) {
        const int j = l + (mi << 5);
        const float4* kr = (const float4*)(kb + (size_t)j*256);
        float a = 0.f;
        #pragma unroll
        for (int w = 0; w < 8; ++w) {
            float4 kv = kr[w], qv = qr[w];
            a += kv.x*qv.x + kv.y*qv.y + kv.z*qv.z + kv.w*qv.w;
        }
        float s0 = a + sb[h*512 + j];
        sc[mi] = s0;
        pmax = fmaxf(pmax, s0);
    }
    #pragma unroll
    for (int o = 16; o >= 1; o >>= 1) pmax = fmaxf(pmax, __shfl_xor(pmax, o));
    float psum = 0.f;
    #pragma unroll
    for (int mi = 0; mi < 16; ++mi) {
        float p = __expf(sc[mi] - pmax);
        sp[h*512 + l + (mi << 5)] = p;
        psum += p;
    }
    #pragma unroll
    for (int o = 16; o >= 1; o >>= 1) psum += __shfl_xor(psum, o);
    if (l == 0) sden[h] = psum;
    __syncthreads();

    // ---- PV: thread t owns output channel t (= h*32+l); coalesced v reads ----
    const float* vb = vg + ((size_t)b << 9)*256 + t;
    const float* spr = &sp[h*512];
    float a0 = 0.f, a1 = 0.f, a2 = 0.f, a3 = 0.f;
    for (int j = 0; j < 512; j += 4) {
        a0 = fmaf(spr[j],   vb[(size_t)(j)*256],   a0);
        a1 = fmaf(spr[j+1], vb[(size_t)(j+1)*256], a1);
        a2 = fmaf(spr[j+2], vb[(size_t)(j+2)*256], a2);
        a3 = fmaf(spr[j+3], vb[(size_t)(j+3)*256], a3);
    }
    ao[(size_t)bi*256 + t] = (a0+a1+a2+a3) / sden[h];
}

// ---------------- output projection + residual ----------------
__global__ __launch_bounds__(256) void k_proj(
    const float* __restrict__ at, const float* __restrict__ Wo,
    const float* __restrict__ bo, const float* __restrict__ x,
    float* __restrict__ x1)
{
    const int row = blockIdx.x, t = threadIdx.x;
    __shared__ float sa[256];
    sa[t] = at[row*256 + t];
    __syncthreads();
    float acc = bo[t];
    for (int d = 0; d < 256; ++d) acc = fmaf(sa[d], Wo[d*256 + t], acc);
    x1[row*256 + t] = acc + x[row*256 + t];
}

// ---------------- FFN: LN -> W1 -> gelu -> W2 -> residual -> f32 out ----------------
__global__ __launch_bounds__(256) void k_ff(
    const float* __restrict__ x1, const float* __restrict__ g,
    const float* __restrict__ bb,
    const float* __restrict__ W1, const float* __restrict__ b1,
    const float* __restrict__ W2, const float* __restrict__ b2,
    float* __restrict__ out)
{
    const int row = blockIdx.x, t = threadIdx.x;
    __shared__ float sh[256];
    __shared__ float sf[1024];
    __shared__ float red[4];
    float xv = x1[row*256 + t];
    float s1 = blockSum256(xv, red);
    float s2 = blockSum256(xv*xv, red);
    float m = s1*(1.f/256.f);
    float rinv = rsqrtf(s2*(1.f/256.f) - m*m + EPS_);
    sh[t] = (xv - m)*rinv*g[t] + bb[t];
    __syncthreads();
    float a0 = b1[t], a1 = b1[t+256], a2 = b1[t+512], a3 = b1[t+768];
    for (int d = 0; d < 256; ++d) {
        float s = sh[d];
        const float* wr = W1 + d*1024 + t;
        a0 = fmaf(s, wr[0],   a0);
        a1 = fmaf(s, wr[256], a1);
        a2 = fmaf(s, wr[512], a2);
        a3 = fmaf(s, wr[768], a3);
    }
    sf[t]     = gelu_(a0);
    sf[t+256] = gelu_(a1);
    sf[t+512] = gelu_(a2);
    sf[t+768] = gelu_(a3);
    __syncthreads();
    float acc = b2[t];
    for (int kk = 0; kk < 1024; ++kk) acc = fmaf(sf[kk], W2[kk*256 + t], acc);
    out[row*256 + t] = acc + xv;
}

extern "C" void kernel_launch(void* const* d_in, const int* in_sizes, int n_in,
                              void* d_out, int out_size, void* d_ws, size_t ws_size,
                              hipStream_t stream) {
    const float* x   = (const float*)d_in[0];
    const float* ef  = (const float*)d_in[1];
    const int*   am  = (const int*)d_in[2];
    const float* ng  = (const float*)d_in[3];
    const float* nb  = (const float*)d_in[4];
    const float* eg  = (const float*)d_in[5];
    const float* ebb = (const float*)d_in[6];
    const float* Wq  = (const float*)d_in[7];
    const float* bq  = (const float*)d_in[8];
    const float* Wk  = (const float*)d_in[9];
    const float* bk  = (const float*)d_in[10];
    const float* Wv  = (const float*)d_in[11];
    const float* bv  = (const float*)d_in[12];
    const float* Wo  = (const float*)d_in[13];
    const float* bo  = (const float*)d_in[14];
    const float* We  = (const float*)d_in[15];
    const float* be  = (const float*)d_in[16];
    const float* fg  = (const float*)d_in[17];
    const float* fb  = (const float*)d_in[18];
    const float* W1  = (const float*)d_in[19];
    const float* b1  = (const float*)d_in[20];
    const float* W2  = (const float*)d_in[21];
    const float* b2  = (const float*)d_in[22];

    float* ws  = (float*)d_ws;
    float* GW  = ws;                      // 2048 f
    float* Av  = ws + 2048;               // 8 f
    float* Cv  = ws + 2064;               // 8 f
    float* q   = ws + 4096;               // 262144 f (B,N,D)
    float* k   = q  + 262144;
    float* v   = k  + 262144;
    float* ao  = v  + 262144;             // 262144 f (B,N,D)
    float* x1  = ao + 262144;             // 262144 f  -> total ~5.3 MB

    hipLaunchKernelGGL(k_setup, dim3(1), dim3(256), 0, stream, eg, ebb, We, be, GW, Av, Cv);
    hipLaunchKernelGGL(k_qkv, dim3(1024), dim3(256), 0, stream,
                       x, ng, nb, Wq, bq, Wk, bk, Wv, bv, q, k, v);
    hipLaunchKernelGGL(k_eattn, dim3(1024), dim3(256), 0, stream,
                       (const float4*)ef, am, GW, Av, Cv, q, k, v, ao);
    hipLaunchKernelGGL(k_proj, dim3(1024), dim3(256), 0, stream, ao, Wo, bo, x, x1);
    hipLaunchKernelGGL(k_ff, dim3(1024), dim3(256), 0, stream,
                       x1, fg, fb, W1, b1, W2, b2, (float*)d_out);
}